// Round 3
// baseline (1444.695 us; speedup 1.0000x reference)
//
#include <hip/hip_runtime.h>
#include <math.h>

#define N_NODES 100000
#define N_NNZ   1000000
#define F_IN    1433
#define F_HID   128
#define F_OUT   64
#define N_POS   20000
#define N_NEG   20000
#define EPS_PN  1e-6f
#define NPART   2048        // spmm grid / colsum partial count

typedef float f32x2   __attribute__((ext_vector_type(2)));
typedef float f32x4   __attribute__((ext_vector_type(4)));
typedef float f32x4u  __attribute__((ext_vector_type(4), aligned(4)));
typedef short bf16x8  __attribute__((ext_vector_type(8)));
typedef short bf16x4  __attribute__((ext_vector_type(4)));

__device__ inline short f2bf(float f) {
  union { float f; unsigned u; } x; x.f = f;
  unsigned r = x.u + 0x7fff + ((x.u >> 16) & 1);   // round-to-nearest-even
  return (short)(r >> 16);
}

// ---- W cast+transpose: Wt[n][k] (bf16, Kp-padded) from W[k][n] fp32 --------
__global__ __launch_bounds__(256) void wcast_kernel(
    const float* __restrict__ W, short* __restrict__ Wt, int K, int Kp, int N) {
  int idx = blockIdx.x * blockDim.x + threadIdx.x;
  if (idx >= N * Kp) return;
  int n = idx / Kp, k = idx - n * Kp;
  float v = (k < K) ? W[(long long)k * N + n] : 0.0f;
  Wt[idx] = f2bf(v);
}

// ---- MFMA GEMM, register-prefetch double buffering -------------------------
// If NORM: A-element is transformed on load as (a - csum[k]*invM) * rn[row]
// (PairNorm of the PREVIOUS layer fused into this GEMM's load).
template<int BMt, int BNt, int WM, int WN, bool NORM>
__global__ __launch_bounds__(256) void mfma_gemm(
    const float* __restrict__ A, const short* __restrict__ Wt,
    float* __restrict__ C, int M, int K, int Kp, int N,
    const float* __restrict__ csum, const float* __restrict__ rn, float invM) {
  constexpr int LD  = 40;                      // LDS row stride in shorts
  constexpr int MI  = BMt / (WM * 16);
  constexpr int NJ  = BNt / (WN * 16);
  constexpr int APF = (BMt * 32) / (256 * 4);  // f32x4 loads of A per thread
  constexpr int WPF = (BNt * 32) / (256 * 8);  // bf16x8 loads of W per thread
  __shared__ __align__(16) short As[BMt * LD];
  __shared__ __align__(16) short Ws[BNt * LD];
  int tid = threadIdx.x;
  int lane = tid & 63, w = tid >> 6;
  int wm = w % WM, wn = w / WM;
  int row0 = blockIdx.x * BMt;
  int ml = lane & 15, kgrp = lane >> 4;

  f32x4 acc[MI][NJ] = {};
  f32x4 pa[APF];
  bf16x8 pw[WPF];

  auto load_a = [&](int k0, f32x4* dst) {
#pragma unroll
    for (int q = 0; q < APF; ++q) {
      int idx = tid + q * 256;
      int r = idx >> 3, k4 = (idx & 7) * 4;
      int gr = row0 + r, gk = k0 + k4;
      f32x4 v = {0.f, 0.f, 0.f, 0.f};
      if (gr < M) {
        float scale = NORM ? rn[gr] : 1.0f;
        if (gk + 3 < K) {
          v = *(const f32x4u*)&A[(long long)gr * K + gk];
          if (NORM) {
            f32x4 m = *(const f32x4u*)&csum[gk];
            v = (v - m * invM) * scale;
          }
        } else {
#pragma unroll
          for (int i = 0; i < 4; ++i)
            if (gk + i < K) {
              float t = A[(long long)gr * K + gk + i];
              if (NORM) t = (t - csum[gk + i] * invM) * scale;
              v[i] = t;
            }
        }
      }
      dst[q] = v;
    }
  };
  auto load_w = [&](int k0, bf16x8* dst) {
#pragma unroll
    for (int q = 0; q < WPF; ++q) {
      int idx = tid + q * 256;
      int n = idx >> 2, kk8 = (idx & 3) * 8;
      dst[q] = *(const bf16x8*)&Wt[(long long)n * Kp + k0 + kk8];
    }
  };

  load_a(0, pa);
  load_w(0, pw);

  for (int k0 = 0; k0 < Kp; k0 += 32) {
#pragma unroll
    for (int q = 0; q < APF; ++q) {
      int idx = tid + q * 256;
      int r = idx >> 3, k4 = (idx & 7) * 4;
      bf16x4 b;
#pragma unroll
      for (int i = 0; i < 4; ++i) b[i] = f2bf(pa[q][i]);
      *(bf16x4*)&As[r * LD + k4] = b;
    }
#pragma unroll
    for (int q = 0; q < WPF; ++q) {
      int idx = tid + q * 256;
      int n = idx >> 2, kk8 = (idx & 3) * 8;
      *(bf16x8*)&Ws[n * LD + kk8] = pw[q];
    }
    __syncthreads();

    if (k0 + 32 < Kp) {           // prefetch next tile during MFMAs
      load_a(k0 + 32, pa);
      load_w(k0 + 32, pw);
    }

    bf16x8 af[MI], bfr[NJ];
#pragma unroll
    for (int i = 0; i < MI; ++i)
      af[i] = *(const bf16x8*)&As[(wm * MI * 16 + i * 16 + ml) * LD + kgrp * 8];
#pragma unroll
    for (int j = 0; j < NJ; ++j)
      bfr[j] = *(const bf16x8*)&Ws[(wn * NJ * 16 + j * 16 + ml) * LD + kgrp * 8];
#pragma unroll
    for (int i = 0; i < MI; ++i)
#pragma unroll
      for (int j = 0; j < NJ; ++j)
        acc[i][j] = __builtin_amdgcn_mfma_f32_16x16x32_bf16(
            af[i], bfr[j], acc[i][j], 0, 0, 0);
    __syncthreads();
  }

  // epilogue: D mapping col = lane&15, row = (lane>>4)*4 + rr
#pragma unroll
  for (int i = 0; i < MI; ++i)
#pragma unroll
    for (int j = 0; j < NJ; ++j)
#pragma unroll
      for (int rr = 0; rr < 4; ++rr) {
        int gr = row0 + wm * MI * 16 + i * 16 + kgrp * 4 + rr;
        int gc = wn * NJ * 16 + j * 16 + ml;
        if (gr < M) C[(long long)gr * N + gc] = acc[i][j][rr];
      }
}

// ---------------- CSR build -------------------------------------------------
__global__ __launch_bounds__(256) void hist_kernel(
    const int* __restrict__ row, int* __restrict__ cnt, int nnz) {
  int i = blockIdx.x * blockDim.x + threadIdx.x;
  if (i < nnz) atomicAdd(&cnt[row[i]], 1);
}

// two-level coalesced scan: (1) per-block int4 local exclusive scan + totals
__global__ __launch_bounds__(256) void scan_local_kernel(
    const int* __restrict__ cnt, int* __restrict__ exc,
    int* __restrict__ btot, int n) {
  __shared__ int sh[256];
  int b = blockIdx.x, t = threadIdx.x;
  int base = b * 1024 + t * 4;
  int4 v = {0, 0, 0, 0};
  if (base + 3 < n) v = *(const int4*)&cnt[base];
  else {
    if (base + 0 < n) v.x = cnt[base + 0];
    if (base + 1 < n) v.y = cnt[base + 1];
    if (base + 2 < n) v.z = cnt[base + 2];
    if (base + 3 < n) v.w = cnt[base + 3];
  }
  int s0 = v.x, s1 = s0 + v.y, s2 = s1 + v.z, s3 = s2 + v.w;
  sh[t] = s3;
  __syncthreads();
  for (int off = 1; off < 256; off <<= 1) {
    int x = (t >= off) ? sh[t - off] : 0;
    __syncthreads();
    sh[t] += x;
    __syncthreads();
  }
  int thOff = sh[t] - s3;                  // exclusive offset within block
  if (t == 255) btot[b] = sh[255];
  int4 e;
  e.x = thOff; e.y = thOff + s0; e.z = thOff + s1; e.w = thOff + s2;
  if (base + 3 < n) *(int4*)&exc[base] = e;
  else {
    if (base + 0 < n) exc[base + 0] = e.x;
    if (base + 1 < n) exc[base + 1] = e.y;
    if (base + 2 < n) exc[base + 2] = e.z;
    if (base + 3 < n) exc[base + 3] = e.w;
  }
}

// (2) add block offsets, emit row_ptr + cursor (exc may alias cursor)
__global__ __launch_bounds__(256) void scan_apply_kernel(
    const int* __restrict__ exc, const int* __restrict__ btot,
    int* __restrict__ row_ptr, int* __restrict__ cursor,
    int n, int nnz, int nb) {
  int b = blockIdx.x, t = threadIdx.x;
  int off = 0;
  for (int i = 0; i < b; ++i) off += btot[i];
  int base = b * 1024 + t * 4;
#pragma unroll
  for (int i = 0; i < 4; ++i) {
    int idx = base + i;
    if (idx < n) {
      int val = exc[idx] + off;
      row_ptr[idx] = val;
      cursor[idx]  = val;
    }
  }
  if (b == nb - 1 && t == 0) row_ptr[n] = nnz;
}

// scatter packed (col, val) pairs -> single 8B store per nnz
__global__ __launch_bounds__(256) void scatter_kernel(
    const int* __restrict__ row, const int* __restrict__ col,
    const float* __restrict__ val, int* __restrict__ cursor,
    int2* __restrict__ cv, int nnz) {
  int i = blockIdx.x * blockDim.x + threadIdx.x;
  if (i >= nnz) return;
  int p = atomicAdd(&cursor[row[i]], 1);
  int2 q; q.x = col[i]; q.y = __float_as_int(val[i]);
  cv[p] = q;
}

// ---- CSR SpMM fused bias+relu+colsum-partial, F=128 ------------------------
// 2 rows per wave, half-wave (32 lanes) per row, lane q owns feats {4q..4q+3}.
// Inner loop: always 4 independent gathers per iteration; tail handled by
// clamping indices to the last nnz and zeroing overflow weights (dup gathers
// hit L1) -> no serially-dependent remainder chain.
__global__ __launch_bounds__(256) void spmm128_fused_kernel(
    const int* __restrict__ rp, const int2* __restrict__ cv,
    const float* __restrict__ sup, const float* __restrict__ bias,
    float* __restrict__ z, float* __restrict__ part, int M) {
  int w = threadIdx.x >> 6, lane = threadIdx.x & 63;
  int q = lane & 31, h = lane >> 5;
  int gw = blockIdx.x * 4 + w;
  const int GW = gridDim.x * 4;
  f32x4 b4 = *(const f32x4*)&bias[q * 4];
  f32x4 cs = {0.f, 0.f, 0.f, 0.f};
  for (int r = gw * 2 + h; r < M; r += GW * 2) {
    int j0 = rp[r], j1 = rp[r + 1];
    f32x4 a = {0.f, 0.f, 0.f, 0.f};
    for (int j = j0; j < j1; j += 4) {
      int jm = j1 - 1;
      int jb = (j + 1 < jm) ? j + 1 : jm;
      int jc = (j + 2 < jm) ? j + 2 : jm;
      int jd = (j + 3 < jm) ? j + 3 : jm;
      int2 c0 = cv[j], c1 = cv[jb], c2 = cv[jc], c3 = cv[jd];
      float v0 = __int_as_float(c0.y);
      float v1 = (j + 1 < j1) ? __int_as_float(c1.y) : 0.f;
      float v2 = (j + 2 < j1) ? __int_as_float(c2.y) : 0.f;
      float v3 = (j + 3 < j1) ? __int_as_float(c3.y) : 0.f;
      f32x4 s0 = *(const f32x4*)&sup[(long long)c0.x * 128 + q * 4];
      f32x4 s1 = *(const f32x4*)&sup[(long long)c1.x * 128 + q * 4];
      f32x4 s2 = *(const f32x4*)&sup[(long long)c2.x * 128 + q * 4];
      f32x4 s3 = *(const f32x4*)&sup[(long long)c3.x * 128 + q * 4];
      a += s0 * v0 + s1 * v1 + s2 * v2 + s3 * v3;
    }
    f32x4 zz = a + b4;
    zz.x = zz.x > 0.f ? zz.x : 0.f;
    zz.y = zz.y > 0.f ? zz.y : 0.f;
    zz.z = zz.z > 0.f ? zz.z : 0.f;
    zz.w = zz.w > 0.f ? zz.w : 0.f;
    cs += zz;
    *(f32x4*)&z[(long long)r * 128 + q * 4] = zz;
  }
  __shared__ f32x4 red[4][64];
  red[w][lane] = cs;
  __syncthreads();
  if (w == 0 && lane < 32) {
    f32x4 t = red[0][q] + red[1][q] + red[2][q] + red[3][q]
            + red[0][q + 32] + red[1][q + 32] + red[2][q + 32] + red[3][q + 32];
    *(f32x4*)&part[(long long)blockIdx.x * 128 + q * 4] = t;
  }
}

// ---- CSR SpMM fused bias+relu+colsum-partial, F=64 -------------------------
__global__ __launch_bounds__(256) void spmm64_fused_kernel(
    const int* __restrict__ rp, const int2* __restrict__ cv,
    const float* __restrict__ sup, const float* __restrict__ bias,
    float* __restrict__ z, float* __restrict__ part, int M) {
  int w = threadIdx.x >> 6, lane = threadIdx.x & 63;
  int q = lane & 31, h = lane >> 5;
  int gw = blockIdx.x * 4 + w;
  const int GW = gridDim.x * 4;
  f32x2 b2 = *(const f32x2*)&bias[q * 2];
  f32x2 cs = {0.f, 0.f};
  for (int r = gw * 2 + h; r < M; r += GW * 2) {
    int j0 = rp[r], j1 = rp[r + 1];
    f32x2 a = {0.f, 0.f};
    for (int j = j0; j < j1; j += 4) {
      int jm = j1 - 1;
      int jb = (j + 1 < jm) ? j + 1 : jm;
      int jc = (j + 2 < jm) ? j + 2 : jm;
      int jd = (j + 3 < jm) ? j + 3 : jm;
      int2 c0 = cv[j], c1 = cv[jb], c2 = cv[jc], c3 = cv[jd];
      float v0 = __int_as_float(c0.y);
      float v1 = (j + 1 < j1) ? __int_as_float(c1.y) : 0.f;
      float v2 = (j + 2 < j1) ? __int_as_float(c2.y) : 0.f;
      float v3 = (j + 3 < j1) ? __int_as_float(c3.y) : 0.f;
      f32x2 s0 = *(const f32x2*)&sup[(long long)c0.x * 64 + q * 2];
      f32x2 s1 = *(const f32x2*)&sup[(long long)c1.x * 64 + q * 2];
      f32x2 s2 = *(const f32x2*)&sup[(long long)c2.x * 64 + q * 2];
      f32x2 s3 = *(const f32x2*)&sup[(long long)c3.x * 64 + q * 2];
      a += s0 * v0 + s1 * v1 + s2 * v2 + s3 * v3;
    }
    f32x2 zz = a + b2;
    zz.x = zz.x > 0.f ? zz.x : 0.f;
    zz.y = zz.y > 0.f ? zz.y : 0.f;
    cs += zz;
    *(f32x2*)&z[(long long)r * 64 + q * 2] = zz;
  }
  __shared__ f32x2 red[4][64];
  red[w][lane] = cs;
  __syncthreads();
  if (w == 0 && lane < 32) {
    f32x2 t = red[0][q] + red[1][q] + red[2][q] + red[3][q]
            + red[0][q + 32] + red[1][q + 32] + red[2][q + 32] + red[3][q + 32];
    *(f32x2*)&part[(long long)blockIdx.x * 64 + q * 2] = t;
  }
}

// ---- reduce NPART partial colsums -> csum[F] (single block, no atomics) ----
__global__ __launch_bounds__(1024) void colsum_reduce_kernel(
    const float* __restrict__ part, float* __restrict__ csum, int F) {
  __shared__ float buf[1024];
  int t = threadIdx.x;
  int S = 1024 / F;
  int f = t % F, s = t / F;
  float a = 0.f;
  for (int bk = s; bk < NPART; bk += S) a += part[(long long)bk * F + f];
  buf[t] = a;
  __syncthreads();
  if (t < F) {
    float r = 0.f;
    for (int s2 = 0; s2 < S; ++s2) r += buf[s2 * F + f];
    csum[f] = r;
  }
}

// ---- row norms: rn[r] = 1/sqrt(eps + ||z[r]-mean||^2) (no x write) ---------
__global__ __launch_bounds__(256) void rownorm_kernel(
    const float* __restrict__ z, const float* __restrict__ csum,
    float* __restrict__ rn, int M, int F) {
  int gid = blockIdx.x * blockDim.x + threadIdx.x;
  int r = gid >> 6;
  int lane = threadIdx.x & 63;
  if (r >= M) return;
  const float invM = 1.0f / (float)M;
  float z0 = z[(long long)r * F + lane] - csum[lane] * invM;
  float z1 = 0.f;
  if (F > 64) z1 = z[(long long)r * F + lane + 64] - csum[lane + 64] * invM;
  float ss = z0 * z0 + z1 * z1;
  for (int o = 32; o > 0; o >>= 1) ss += __shfl_down(ss, o);
  if (lane == 0) rn[r] = 1.0f / sqrtf(EPS_PN + ss);
}

// ---------------- decode: sigmoid(dot(pn(z[src]), pn(z[dst]))) --------------
__global__ __launch_bounds__(256) void decode_kernel(
    const int* __restrict__ pos, const int* __restrict__ neg,
    const float* __restrict__ z, const float* __restrict__ csum,
    const float* __restrict__ rn, float* __restrict__ out,
    int npos, int ntot, float invM) {
  int gid = blockIdx.x * blockDim.x + threadIdx.x;
  int e = gid >> 6;
  int lane = threadIdx.x & 63;
  if (e >= ntot) return;
  int src, dst;
  if (e < npos) { src = pos[2 * e];            dst = pos[2 * e + 1]; }
  else          { int q = e - npos; src = neg[2 * q]; dst = neg[2 * q + 1]; }
  float mean = csum[lane] * invM;
  float xs = (z[(long long)src * 64 + lane] - mean) * rn[src];
  float xd = (z[(long long)dst * 64 + lane] - mean) * rn[dst];
  float p = xs * xd;
  for (int o = 32; o > 0; o >>= 1) p += __shfl_down(p, o);
  if (lane == 0) out[e] = 1.0f / (1.0f + expf(-p));
}

extern "C" void kernel_launch(void* const* d_in, const int* in_sizes, int n_in,
                              void* d_out, int out_size, void* d_ws, size_t ws_size,
                              hipStream_t stream) {
  const float* in_feature = (const float*)d_in[0];
  const int*   adj_row    = (const int*)  d_in[1];
  const int*   adj_col    = (const int*)  d_in[2];
  const float* adj_val    = (const float*)d_in[3];
  const int*   pos_ei     = (const int*)  d_in[4];
  const int*   neg_ei     = (const int*)  d_in[5];
  const float* W0 = (const float*)d_in[6];
  const float* b0 = (const float*)d_in[7];
  const float* W1 = (const float*)d_in[8];
  const float* b1 = (const float*)d_in[9];
  const float* W2 = (const float*)d_in[10];
  const float* b2 = (const float*)d_in[11];
  float* out = (float*)d_out;

  char* p = (char*)d_ws;
  auto alloc = [&](size_t bytes) {
    char* r = p;
    p += (bytes + 255) & ~(size_t)255;
    return r;
  };
  const size_t BUF = (size_t)N_NODES * F_HID * sizeof(float);     // 51.2 MB
  float* sup     = (float*)alloc(BUF);
  float* xbuf    = (float*)alloc(BUF);
  short* Wt      = (short*)alloc((size_t)F_HID * 1440 * sizeof(short));
  float* csum    = (float*)alloc(512);
  float* rn      = (float*)alloc((size_t)N_NODES * sizeof(float));
  float* part    = (float*)alloc((size_t)NPART * F_HID * sizeof(float)); // 1 MB
  int*   cnt     = (int*)  alloc((size_t)N_NODES * sizeof(int));
  int*   btot    = (int*)  alloc(1024);
  int*   row_ptr = (int*)  alloc((size_t)(N_NODES + 1) * sizeof(int));
  int*   cursor  = (int*)  alloc((size_t)N_NODES * sizeof(int));
  int2*  cv      = (int2*) alloc((size_t)N_NNZ * sizeof(int2));

  const int NB = (N_NODES + 1023) / 1024;
  const float invM = 1.0f / (float)N_NODES;

  // ---- build CSR (once; reused by all 3 layers) ----
  hipMemsetAsync(cnt, 0, (size_t)N_NODES * sizeof(int), stream);
  hist_kernel<<<(N_NNZ + 255) / 256, 256, 0, stream>>>(adj_row, cnt, N_NNZ);
  scan_local_kernel<<<NB, 256, 0, stream>>>(cnt, cursor, btot, N_NODES);
  scan_apply_kernel<<<NB, 256, 0, stream>>>(cursor, btot, row_ptr, cursor,
                                            N_NODES, N_NNZ, NB);
  scatter_kernel<<<(N_NNZ + 255) / 256, 256, 0, stream>>>(
      adj_row, adj_col, adj_val, cursor, cv, N_NNZ);

  // ---- layer 1: K=1433 -> F=128, no input normalization ----
  {
    int K = F_IN, Kp = ((K + 31) / 32) * 32, F = F_HID;
    wcast_kernel<<<(F * Kp + 255) / 256, 256, 0, stream>>>(W0, Wt, K, Kp, F);
    mfma_gemm<128, 128, 2, 2, false><<<(N_NODES + 127) / 128, 256, 0, stream>>>(
        in_feature, Wt, sup, N_NODES, K, Kp, F, nullptr, nullptr, 0.f);
    spmm128_fused_kernel<<<NPART, 256, 0, stream>>>(
        row_ptr, cv, sup, b0, xbuf, part, N_NODES);
    colsum_reduce_kernel<<<1, 1024, 0, stream>>>(part, csum, F);
    rownorm_kernel<<<(N_NODES * 64 + 255) / 256, 256, 0, stream>>>(
        xbuf, csum, rn, N_NODES, F);
  }
  // ---- layer 2: K=128 -> F=128, PairNorm(L1) fused into GEMM load ----
  {
    int K = F_HID, Kp = K, F = F_HID;
    wcast_kernel<<<(F * Kp + 255) / 256, 256, 0, stream>>>(W1, Wt, K, Kp, F);
    mfma_gemm<128, 128, 2, 2, true><<<(N_NODES + 127) / 128, 256, 0, stream>>>(
        xbuf, Wt, sup, N_NODES, K, Kp, F, csum, rn, invM);
    spmm128_fused_kernel<<<NPART, 256, 0, stream>>>(
        row_ptr, cv, sup, b1, xbuf, part, N_NODES);
    colsum_reduce_kernel<<<1, 1024, 0, stream>>>(part, csum, F);
    rownorm_kernel<<<(N_NODES * 64 + 255) / 256, 256, 0, stream>>>(
        xbuf, csum, rn, N_NODES, F);
  }
  // ---- layer 3: K=128 -> F=64, PairNorm(L2) fused into GEMM load ----
  {
    int K = F_HID, Kp = K, F = F_OUT;
    wcast_kernel<<<(F * Kp + 255) / 256, 256, 0, stream>>>(W2, Wt, K, Kp, F);
    mfma_gemm<128, 64, 2, 2, true><<<(N_NODES + 127) / 128, 256, 0, stream>>>(
        xbuf, Wt, sup, N_NODES, K, Kp, F, csum, rn, invM);
    spmm64_fused_kernel<<<NPART, 256, 0, stream>>>(
        row_ptr, cv, sup, b2, xbuf, part, N_NODES);
    colsum_reduce_kernel<<<1, 1024, 0, stream>>>(part, csum, F);
    rownorm_kernel<<<(N_NODES * 64 + 255) / 256, 256, 0, stream>>>(
        xbuf, csum, rn, N_NODES, F);
  }
  // ---- decode: PairNorm(L3) applied on the fly ----
  decode_kernel<<<((N_POS + N_NEG) * 64 + 255) / 256, 256, 0, stream>>>(
      pos_ei, neg_ei, xbuf, csum, rn, out, N_POS, N_POS + N_NEG, invM);
}